// Round 7
// baseline (264.102 us; speedup 1.0000x reference)
//
#include <hip/hip_runtime.h>

typedef float f32x2 __attribute__((ext_vector_type(2)));

#define IMG_W 512
#define IMG_H 512
#define TY 8
#define TX 256
#define ENT 272                   // padded entry-columns per tile (8|256|8)
#define ATOMS 136                 // ENT/2 atoms of 16 B per slab
#define SLAB_BYTES (ATOMS * 16)   // 2176 B
#define NSLAB 20                  // 5 maps x 4 row-pairs
#define PLANES 96                 // N*C
#define NPIX (32ll * 3 * 512 * 512)
#define NACC 64                   // atomic fanout slots

// Separable Gaussian, sigma=1.5, size=11, normalized (compile-time folded).
#define WG_INIT { 0.00102838f, 0.00759876f, 0.03600077f, 0.10936069f, \
                  0.21300553f, 0.26601172f, 0.21300553f, 0.10936069f, \
                  0.03600077f, 0.00759876f, 0.00102838f }

// Entry e = f32x2{row 2rp, row 2rp+1} at image col (xent0 + e).
// Atom at = e>>1 (16 B). XOR swizzle: reads (lane g -> atoms 2g+1..2g+8)
// hit distinct bank-quads per 8-lane phase (<=1 residual 2-way on odd
// offsets); writes (consecutive atoms) are conflict-free.
__device__ __forceinline__ int swz(int at) { return at ^ ((at >> 3) & 7); }

__global__ __launch_bounds__(256)   // no min-waves arg (R2: forced cap -> spill)
void ssim_main(const float* __restrict__ pred, const float* __restrict__ targ,
               double* __restrict__ acc) {
    const float WG[11] = WG_INIT;

    __shared__ __align__(16) unsigned char ldsraw[NSLAB * SLAB_BYTES]; // 43520 B
    __shared__ float wsum[4];

    const int tid   = threadIdx.x;
    const int plane = blockIdx.z;
    const int y0    = blockIdx.y * TY;
    const int xent0 = blockIdx.x * TX - 8;   // image col of entry 0
    const size_t base = (size_t)plane * (IMG_W * IMG_H);

    // ---- vertical pass for entry-column e (image col xent0+e) ----
    // OOB columns/rows produce zeros -> pads need no separate zeroing.
    auto do_col = [&](int e) {
        const int  cx  = xent0 + e;
        const bool okx = (unsigned)cx < (unsigned)IMG_W;
        const size_t cb = base + (size_t)(okx ? cx : 0);

        float pv[TY + 10], tv[TY + 10];
#pragma unroll
        for (int iy = 0; iy < TY + 10; ++iy) {
            const int  y  = y0 - 5 + iy;
            const bool ok = okx && ((unsigned)y < (unsigned)IMG_H);
            pv[iy] = ok ? pred[cb + (size_t)y * IMG_W] : 0.f;
            tv[iy] = ok ? targ[cb + (size_t)y * IMG_W] : 0.f;
        }

        f32x2 A[5][4];
#pragma unroll
        for (int m = 0; m < 5; ++m)
#pragma unroll
            for (int rp = 0; rp < 4; ++rp) A[m][rp] = (f32x2){0.f, 0.f};

#pragma unroll
        for (int iy = 0; iy < TY + 10; ++iy) {
            const float p = pv[iy], t = tv[iy];
            const float pp = p * p, tt = t * t, pt = p * t;
            const f32x2 vs[5] = { {p,p}, {t,t}, {pp,pp}, {tt,tt}, {pt,pt} };
#pragma unroll
            for (int rp = 0; rp < 4; ++rp) {
                const int a = iy - 2 * rp;                      // compile-time
                if (a < 0 || a > 11) continue;                  // both lanes zero
                const float w0 = (a <= 10) ? WG[a] : 0.f;       // row 2rp
                const float w1 = (a >= 1)  ? WG[a - 1] : 0.f;   // row 2rp+1
                const f32x2 w = (f32x2){w0, w1};
#pragma unroll
                for (int m = 0; m < 5; ++m)
                    A[m][rp] = __builtin_elementwise_fma(vs[m], w, A[m][rp]);
            }
        }

        const int bof = swz(e >> 1) * 16 + (e & 1) * 8;
#pragma unroll
        for (int m = 0; m < 5; ++m)
#pragma unroll
            for (int rp = 0; rp < 4; ++rp)
                *(f32x2*)(ldsraw + (m * 4 + rp) * SLAB_BYTES + bof) = A[m][rp];
    };

    do_col(tid);                          // entries 0..255
    if (tid < ENT - TX) do_col(TX + tid); // halo entries 256..271 (regs reused)
    __syncthreads();                      // the ONLY phase barrier

    // ---- horizontal pass + SSIM: wave = row-pair, lane = 4-col group ----
    // lane g: atoms 2g+1..2g+8 = entries 4g+2..4g+17; out cols 4g..4g+3
    // (out col j taps entries j+3..j+13 -> win[d+1+k], win[i] = entry 4g+2+i).
    const float C1 = 1e-4f, C2 = 9e-4f;
    const int rp = tid >> 6;           // wave -> row pair
    const int g  = tid & 63;           // lane -> col group
    float lsum = 0.f;

    f32x2 H[5][4];
#pragma unroll
    for (int m = 0; m < 5; ++m) {
        const unsigned char* slab = ldsraw + (m * 4 + rp) * SLAB_BYTES;
        f32x2 win[16];
#pragma unroll
        for (int q = 0; q < 8; ++q) {
            const float4 v = *(const float4*)(slab + swz(2 * g + 1 + q) * 16);
            win[2*q]   = (f32x2){v.x, v.y};
            win[2*q+1] = (f32x2){v.z, v.w};
        }
#pragma unroll
        for (int d = 0; d < 4; ++d) {
            f32x2 h = (f32x2){0.f, 0.f};
#pragma unroll
            for (int k = 0; k < 11; ++k) {
                const f32x2 wk = (f32x2){WG[k], WG[k]};
                h = __builtin_elementwise_fma(win[d + 1 + k], wk, h);
            }
            H[m][d] = h;
        }
    }

#pragma unroll
    for (int d = 0; d < 4; ++d) {
        f32x2 mu1 = H[0][d], mu2 = H[1][d];
        f32x2 mu1s = mu1 * mu1, mu2s = mu2 * mu2, mu12 = mu1 * mu2;
        f32x2 s1  = H[2][d] - mu1s;
        f32x2 s2  = H[3][d] - mu2s;
        f32x2 s12 = H[4][d] - mu12;
        f32x2 num = (mu12 + mu12 + (f32x2){C1, C1}) *
                    (s12 + s12 + (f32x2){C2, C2});
        f32x2 den = (mu1s + mu2s + (f32x2){C1, C1}) *
                    (s1 + s2 + (f32x2){C2, C2}) + (f32x2){1e-8f, 1e-8f};
        lsum += num.x * __builtin_amdgcn_rcpf(den.x);
        lsum += num.y * __builtin_amdgcn_rcpf(den.y);
    }

    // ---- reduction: wave shuffle -> LDS -> one atomic per block (fanout) ----
#pragma unroll
    for (int off = 32; off > 0; off >>= 1)
        lsum += __shfl_down(lsum, off);
    if ((tid & 63) == 0) wsum[tid >> 6] = lsum;
    __syncthreads();
    if (tid == 0) {
        const int bid = (blockIdx.z * gridDim.y + blockIdx.y) * gridDim.x
                        + blockIdx.x;
        atomicAdd(&acc[bid & (NACC - 1)],
                  (double)(wsum[0] + wsum[1] + wsum[2] + wsum[3]));
    }
}

__global__ void ssim_final(const double* __restrict__ acc, float* __restrict__ out) {
    double s = 0.0;
#pragma unroll
    for (int i = 0; i < NACC; ++i) s += acc[i];
    out[0] = 1.0f - (float)(s * (1.0 / (double)NPIX));
}

extern "C" void kernel_launch(void* const* d_in, const int* in_sizes, int n_in,
                              void* d_out, int out_size, void* d_ws, size_t ws_size,
                              hipStream_t stream) {
    const float* pred = (const float*)d_in[0];
    const float* targ = (const float*)d_in[1];
    double* acc = (double*)d_ws;

    hipMemsetAsync(acc, 0, NACC * sizeof(double), stream);

    dim3 grid(IMG_W / TX, IMG_H / TY, PLANES);   // (2, 64, 96) = 12288 blocks
    ssim_main<<<grid, 256, 0, stream>>>(pred, targ, acc);
    ssim_final<<<1, 1, 0, stream>>>(acc, (float*)d_out);
}